// Round 3
// baseline (1116.918 us; speedup 1.0000x reference)
//
#include <hip/hip_runtime.h>

#define N_NODES 50000
#define N_EDGES 1600000
#define D_IN 192
#define D_HID 128

typedef __bf16 bf16x8 __attribute__((ext_vector_type(8)));
typedef float f32x4 __attribute__((ext_vector_type(4)));

__device__ __forceinline__ unsigned short f2b(float x) {
    unsigned u = __builtin_bit_cast(unsigned, x);
    u += 0x7FFFu + ((u >> 16) & 1u);          // round-to-nearest-even
    return (unsigned short)(u >> 16);
}
__device__ __forceinline__ float blo(unsigned u) {   // low ushort = feature 2f
    return __builtin_bit_cast(float, u << 16);
}
__device__ __forceinline__ float bhi(unsigned u) {   // high ushort = feature 2f+1
    return __builtin_bit_cast(float, u & 0xFFFF0000u);
}

// ---------------- CSR build ----------------

__global__ void hist_kernel(const int* __restrict__ dst, int E, int* __restrict__ cnt) {
    int e = blockIdx.x * blockDim.x + threadIdx.x;
    if (e < E) atomicAdd(&cnt[dst[e]], 1);
}

// Phase A: per-block (256-elem) partial sums + dhis
__global__ __launch_bounds__(256) void block_sums(const int* __restrict__ cnt, int n,
        int* __restrict__ bsum, float* __restrict__ dhis) {
    __shared__ int sh[256];
    int t = threadIdx.x;
    int i = blockIdx.x * 256 + t;
    int c = (i < n) ? cnt[i] : 0;
    if (i < n) dhis[i] = rsqrtf((float)c + 1.0f);
    sh[t] = c;
    __syncthreads();
    for (int o = 128; o > 0; o >>= 1) {
        if (t < o) sh[t] += sh[t + o];
        __syncthreads();
    }
    if (t == 0) bsum[blockIdx.x] = sh[0];
}

// Phase B: single block scans block sums (nb <= 256)
__global__ __launch_bounds__(256) void scan_bsums(const int* __restrict__ bsum, int nb,
        int* __restrict__ boff, int* __restrict__ row_ptr, int n) {
    __shared__ int sh[256];
    int t = threadIdx.x;
    int v = (t < nb) ? bsum[t] : 0;
    sh[t] = v;
    __syncthreads();
    for (int o = 1; o < 256; o <<= 1) {
        int a = (t >= o) ? sh[t - o] : 0;
        __syncthreads();
        sh[t] += a;
        __syncthreads();
    }
    if (t < nb) boff[t] = sh[t] - v;
    if (t == 255) row_ptr[n] = sh[255];
}

// Phase C: block-local scan + global offset -> row_ptr, fill
__global__ __launch_bounds__(256) void block_scan(const int* __restrict__ cnt, int n,
        const int* __restrict__ boff, int* __restrict__ row_ptr, int* __restrict__ fill) {
    __shared__ int sh[256];
    int t = threadIdx.x;
    int i = blockIdx.x * 256 + t;
    int c = (i < n) ? cnt[i] : 0;
    sh[t] = c;
    __syncthreads();
    for (int o = 1; o < 256; o <<= 1) {
        int a = (t >= o) ? sh[t - o] : 0;
        __syncthreads();
        sh[t] += a;
        __syncthreads();
    }
    if (i < n) {
        int excl = boff[blockIdx.x] + sh[t] - c;
        row_ptr[i] = excl;
        fill[i] = excl;
    }
}

__global__ void fill_kernel(const int* __restrict__ src, const int* __restrict__ dst, int E,
                            int* __restrict__ fill, int* __restrict__ esrc) {
    int e = blockIdx.x * blockDim.x + threadIdx.x;
    if (e < E) {
        int slot = atomicAdd(&fill[dst[e]], 1);
        esrc[slot] = src[e];
    }
}

// ---------------- weight prep: Wt[j][k] = bf16(W[k][j]), all 6 in one launch --------

struct WP { const float* w; unsigned short* wt; int K; };

__global__ void prep_all(WP p0, WP p1, WP p2, WP p3, WP p4, WP p5) {
    WP p;
    switch (blockIdx.y) {
        case 0: p = p0; break; case 1: p = p1; break; case 2: p = p2; break;
        case 3: p = p3; break; case 4: p = p4; break; default: p = p5; break;
    }
    int idx = blockIdx.x * 256 + threadIdx.x;
    if (idx < 128 * p.K) {
        int j = idx / p.K, k = idx - j * p.K;
        p.wt[idx] = f2b(p.w[(size_t)k * 128 + j]);
    }
}

// ---------------- MFMA GEMM: chunked bf16 out[ch][M][32] = A[M,K](lda) @ W + b --------

__global__ __launch_bounds__(256) void gemm_mfma(
        const float* __restrict__ A, int lda, int K, int Kp,
        const unsigned short* __restrict__ Wt, const float* __restrict__ bias,
        unsigned short* __restrict__ out, int M) {
    __shared__ __align__(16) unsigned short As[64 * 200];   // row stride Kp (<=200)

    int tid = threadIdx.x;
    int row0 = blockIdx.x * 64;

    // ---- stage A panel (64 rows x K) as bf16 ----
    {
        int r = tid >> 2;          // 0..63
        int q = tid & 3;
        int grow = row0 + r;
        int crow = grow < M ? grow : (M - 1);
        int kq = K >> 2;           // 48 or 32
        const float* ap = A + (size_t)crow * lda + q * kq;
        unsigned short* sp = As + r * Kp + q * kq;
        for (int k = 0; k < kq; k += 4) {
            float4 v = *(const float4*)(ap + k);
            sp[k + 0] = f2b(v.x); sp[k + 1] = f2b(v.y);
            sp[k + 2] = f2b(v.z); sp[k + 3] = f2b(v.w);
        }
    }
    __syncthreads();

    int wave = tid >> 6, lane = tid & 63;
    int m = lane & 15, quad = lane >> 4;

    f32x4 acc[8];
#pragma unroll
    for (int g = 0; g < 8; ++g) acc[g] = (f32x4){0.f, 0.f, 0.f, 0.f};

    int nsteps = K >> 5;           // 6 or 4
    for (int ks = 0; ks < nsteps; ++ks) {
        int k0 = ks * 32 + quad * 8;
        bf16x8 af = *(const bf16x8*)(As + (wave * 16 + m) * Kp + k0);
#pragma unroll
        for (int g = 0; g < 8; ++g) {
            bf16x8 bfr = *(const bf16x8*)(Wt + (size_t)(g * 16 + m) * K + k0);
            acc[g] = __builtin_amdgcn_mfma_f32_16x16x32_bf16(af, bfr, acc[g], 0, 0, 0);
        }
    }

    // ---- epilogue: C/D layout col=lane&15, row=quad*4+reg; chunked output ----
#pragma unroll
    for (int g = 0; g < 8; ++g) {
        int col = g * 16 + m;
        int ch = col >> 5, wi = col & 31;
        float bv = bias[col];
        unsigned short* ob = out + (size_t)ch * M * 32 + wi;
#pragma unroll
        for (int r = 0; r < 4; ++r) {
            int grow = row0 + wave * 16 + quad * 4 + r;
            if (grow < M) ob[(size_t)grow * 32] = f2b(acc[g][r] + bv);
        }
    }
}

// ---------------- fused dual-view aggregation (one 32-feature chunk) ----------------
// One wave per dst; 4 edge-slots x 16 lanes; lane handles features 2f,2f+1.

__global__ __launch_bounds__(256) void agg_kernel(
        const unsigned* __restrict__ c1, const unsigned* __restrict__ c2,
        const int* __restrict__ row_ptr, const int* __restrict__ esrc,
        const float* __restrict__ dhis, const float* __restrict__ D_inv,
        float* __restrict__ out_q, float* __restrict__ out_p, int n) {
    int wave = threadIdx.x >> 6, lane = threadIdx.x & 63;
    int d = blockIdx.x * 4 + wave;
    if (d >= n) return;
    int g = lane >> 4, f = lane & 15;

    int e0 = row_ptr[d], e1 = row_ptr[d + 1];
    float a1x = 0.f, a1y = 0.f, g1x = 0.f, g1y = 0.f;
    float a2x = 0.f, a2y = 0.f, g2x = 0.f, g2y = 0.f;

    int e = e0;
    for (; e + 8 <= e1; e += 8) {
        int sa = esrc[e + g], sb = esrc[e + 4 + g];
        float da = dhis[sa], db = dhis[sb];
        unsigned u1a = c1[(size_t)sa * 16 + f], u2a = c2[(size_t)sa * 16 + f];
        unsigned u1b = c1[(size_t)sb * 16 + f], u2b = c2[(size_t)sb * 16 + f];
        float v;
        v = blo(u1a); a1x += v; g1x = fmaf(v, da, g1x);
        v = bhi(u1a); a1y += v; g1y = fmaf(v, da, g1y);
        v = blo(u2a); a2x += v; g2x = fmaf(v, da, g2x);
        v = bhi(u2a); a2y += v; g2y = fmaf(v, da, g2y);
        v = blo(u1b); a1x += v; g1x = fmaf(v, db, g1x);
        v = bhi(u1b); a1y += v; g1y = fmaf(v, db, g1y);
        v = blo(u2b); a2x += v; g2x = fmaf(v, db, g2x);
        v = bhi(u2b); a2y += v; g2y = fmaf(v, db, g2y);
    }
    for (; e + 4 <= e1; e += 4) {
        int sa = esrc[e + g];
        float da = dhis[sa];
        unsigned u1a = c1[(size_t)sa * 16 + f], u2a = c2[(size_t)sa * 16 + f];
        float v;
        v = blo(u1a); a1x += v; g1x = fmaf(v, da, g1x);
        v = bhi(u1a); a1y += v; g1y = fmaf(v, da, g1y);
        v = blo(u2a); a2x += v; g2x = fmaf(v, da, g2x);
        v = bhi(u2a); a2y += v; g2y = fmaf(v, da, g2y);
    }
    if (e + g < e1) {
        int sa = esrc[e + g];
        float da = dhis[sa];
        unsigned u1a = c1[(size_t)sa * 16 + f], u2a = c2[(size_t)sa * 16 + f];
        float v;
        v = blo(u1a); a1x += v; g1x = fmaf(v, da, g1x);
        v = bhi(u1a); a1y += v; g1y = fmaf(v, da, g1y);
        v = blo(u2a); a2x += v; g2x = fmaf(v, da, g2x);
        v = bhi(u2a); a2y += v; g2y = fmaf(v, da, g2y);
    }

    // reduce across the 4 edge-slots (lanes differing in bits 4,5)
#define RED(v) v += __shfl_xor(v, 16, 64); v += __shfl_xor(v, 32, 64);
    RED(a1x) RED(a1y) RED(g1x) RED(g1y)
    RED(a2x) RED(a2y) RED(g2x) RED(g2y)
#undef RED

    if (g == 0) {
        float dh = dhis[d];
        float di = D_inv[d];
        float dh2 = dh * dh;
        unsigned us1 = c1[(size_t)d * 16 + f];
        unsigned us2 = c2[(size_t)d * 16 + f];

        float o1x = fmaf(dh, g1x, fmaf(blo(us1), dh2, a2x * di));
        float o1y = fmaf(dh, g1y, fmaf(bhi(us1), dh2, a2y * di));
        float o2x = fmaf(dh, g2x, fmaf(blo(us2), dh2, a1x * di));
        float o2y = fmaf(dh, g2y, fmaf(bhi(us2), dh2, a1y * di));

        *(float2*)(out_q + (size_t)d * 384 + f * 2) =
            make_float2(fmaxf(o1x, 0.f), fmaxf(o1y, 0.f));
        *(float2*)(out_p + (size_t)d * 384 + f * 2) =
            make_float2(fmaxf(o2x, 0.f), fmaxf(o2y, 0.f));
    }
}

// ---------------- launcher ----------------

extern "C" void kernel_launch(void* const* d_in, const int* in_sizes, int n_in,
                              void* d_out, int out_size, void* d_ws, size_t ws_size,
                              hipStream_t stream) {
    const float* x     = (const float*)d_in[0];
    const float* view2 = (const float*)d_in[1];
    const int*   eidx  = (const int*)d_in[2];
    const float* D_inv = (const float*)d_in[3];
    const float* W1 = (const float*)d_in[4];  const float* b1 = (const float*)d_in[5];
    const float* W2 = (const float*)d_in[6];  const float* b2 = (const float*)d_in[7];
    const float* W3 = (const float*)d_in[8];  const float* b3 = (const float*)d_in[9];
    const float* W4 = (const float*)d_in[10]; const float* b4 = (const float*)d_in[11];
    const float* W5 = (const float*)d_in[12]; const float* b5 = (const float*)d_in[13];
    const float* W6 = (const float*)d_in[14]; const float* b6 = (const float*)d_in[15];

    const int n = N_NODES;
    const int E = N_EDGES;
    const int nb = (n + 255) / 256;            // 196
    const int* src  = eidx;
    const int* dstv = eidx + E;

    char* ws = (char*)d_ws;
    size_t off = 0;
    auto alloc = [&](size_t bytes) -> void* {
        void* p = ws + off;
        off += (bytes + 255) & ~(size_t)255;
        return p;
    };
    int*   cnt     = (int*)alloc((size_t)n * 4);
    int*   row_ptr = (int*)alloc((size_t)(n + 1) * 4);
    int*   fill    = (int*)alloc((size_t)n * 4);
    float* dhis    = (float*)alloc((size_t)n * 4);
    int*   bsum    = (int*)alloc((size_t)nb * 4);
    int*   boff    = (int*)alloc((size_t)nb * 4);
    int*   esrc    = (int*)alloc((size_t)E * 4);
    unsigned short* h1b = (unsigned short*)alloc((size_t)n * 128 * 2);
    unsigned short* h2b = (unsigned short*)alloc((size_t)n * 128 * 2);
    unsigned short* Wt1 = (unsigned short*)alloc((size_t)128 * 192 * 2);
    unsigned short* Wt4 = (unsigned short*)alloc((size_t)128 * 192 * 2);
    unsigned short* Wt2 = (unsigned short*)alloc((size_t)128 * 128 * 2);
    unsigned short* Wt3 = (unsigned short*)alloc((size_t)128 * 128 * 2);
    unsigned short* Wt5 = (unsigned short*)alloc((size_t)128 * 128 * 2);
    unsigned short* Wt6 = (unsigned short*)alloc((size_t)128 * 128 * 2);

    float* qb = (float*)d_out;
    float* pb = qb + (size_t)n * 384;
    const unsigned* U1 = (const unsigned*)h1b;
    const unsigned* U2 = (const unsigned*)h2b;

    // --- CSR build ---
    hipMemsetAsync(cnt, 0, (size_t)n * 4, stream);
    int eblocks = (E + 255) / 256;
    hist_kernel<<<eblocks, 256, 0, stream>>>(dstv, E, cnt);
    block_sums<<<nb, 256, 0, stream>>>(cnt, n, bsum, dhis);
    scan_bsums<<<1, 256, 0, stream>>>(bsum, nb, boff, row_ptr, n);
    block_scan<<<nb, 256, 0, stream>>>(cnt, n, boff, row_ptr, fill);
    fill_kernel<<<eblocks, 256, 0, stream>>>(src, dstv, E, fill, esrc);

    // --- weight transposes (bf16), one launch ---
    {
        WP p0{W1, Wt1, 192}, p1{W4, Wt4, 192}, p2{W2, Wt2, 128};
        WP p3{W3, Wt3, 128}, p4{W5, Wt5, 128}, p5{W6, Wt6, 128};
        dim3 grid((128 * 192 + 255) / 256, 6);
        prep_all<<<grid, 256, 0, stream>>>(p0, p1, p2, p3, p4, p5);
    }

    int gblocks = (n + 63) / 64;
    int ablocks = (n + 3) / 4;

    // --- layer 1 ---
    gemm_mfma<<<gblocks, 256, 0, stream>>>(x,     D_IN, 192, 200, Wt1, b1, h1b, n);
    gemm_mfma<<<gblocks, 256, 0, stream>>>(view2, D_IN, 192, 200, Wt4, b4, h2b, n);
    for (int c = 0; c < 4; ++c)
        agg_kernel<<<ablocks, 256, 0, stream>>>(U1 + (size_t)c * n * 16, U2 + (size_t)c * n * 16,
                row_ptr, esrc, dhis, D_inv, qb + c * 32, pb + c * 32, n);

    // --- layer 2 ---
    gemm_mfma<<<gblocks, 256, 0, stream>>>(qb, 384, 128, 136, Wt2, b2, h1b, n);
    gemm_mfma<<<gblocks, 256, 0, stream>>>(pb, 384, 128, 136, Wt5, b5, h2b, n);
    for (int c = 0; c < 4; ++c)
        agg_kernel<<<ablocks, 256, 0, stream>>>(U1 + (size_t)c * n * 16, U2 + (size_t)c * n * 16,
                row_ptr, esrc, dhis, D_inv, qb + 128 + c * 32, pb + 128 + c * 32, n);

    // --- layer 3 ---
    gemm_mfma<<<gblocks, 256, 0, stream>>>(qb + 128, 384, 128, 136, Wt3, b3, h1b, n);
    gemm_mfma<<<gblocks, 256, 0, stream>>>(pb + 128, 384, 128, 136, Wt6, b6, h2b, n);
    for (int c = 0; c < 4; ++c)
        agg_kernel<<<ablocks, 256, 0, stream>>>(U1 + (size_t)c * n * 16, U2 + (size_t)c * n * 16,
                row_ptr, esrc, dhis, D_inv, qb + 256 + c * 32, pb + 256 + c * 32, n);
}